// Round 9
// baseline (172.141 us; speedup 1.0000x reference)
//
#include <hip/hip_runtime.h>

// VectorQuantizer gfx950 R13: NO-LDS argmin — codebook streamed from L2 into
// registers, x resident in registers, 32x32x16 MFMA, 16 waves/CU.
// Ledger: 9 structures (LDS-B, reg-B+LDS-A, gll staging, issue reorder,
// unroll 8, 16-wave code-split, 2-block grids) all 47-66 us with ~77% stall;
// common factor = K-loop fed through LDS at low TLP. R13 eliminates LDS:
//  - 256 blocks x 1024 thr (16 waves, 4/SIMD, ZERO LDS except 64B redbuf).
//  - Wave = 32 rows x 1024 codes via mfma_f32_32x32x16_bf16 (128 MFMA/wave,
//    16-deep acc, half the MFMA instruction count).
//  - B-frags: global_load_dwordx4 from the L2-resident 128 KB bf16 codebook,
//    double-buffered 1 tile ahead (compiler pipelines global loads, unlike
//    the ds_read chains it refused to pipeline in R4..R12).
//  - L2 floor: 16 waves/CU x 128 KB = 2 MB/CU => ~64 MB/XCD / 4.3 TB/s ~ 15 us.
// A layout: A[m=lane&31][k=8*(lane>>5)+j]; B[n=lane&31][k=8*(lane>>5)+j];
// C/D: col n=lane&31, row m=(reg&3)+8*(reg>>2)+4*(lane>>5)  [guide sec3, m74/m101].
// cc = 0.5+||e||^2 is col-indexed => lane-uniform across all 16 acc regs.
// key = (bits(s)&~1023) | code, code = n*32 + (lane&31) lane-constant per tile.
// dist2 = s_rec - 0.5 + ||x||^2 (SSE from keys; no x re-read, no output pass).

typedef __attribute__((ext_vector_type(8))) short short8;
typedef __attribute__((ext_vector_type(4))) float f32x4;
typedef __attribute__((ext_vector_type(16))) float f32x16;

#define VQ_D 64
#define MTILE 512  // rows per block (16 waves x 32 rows)
#define NTH 1024

__device__ inline unsigned short f2bf(float f) {
  union { float f; unsigned u; } v; v.f = f;
  unsigned r = v.u + 0x7FFFu + ((v.u >> 16) & 1u);  // RNE
  return (unsigned short)(r >> 16);
}

// Prep: one wave per codebook row. c2b[k] = 0.5 + ||e_k||^2 ; codebook -> bf16
// (unpadded stride 64 — no LDS staging anymore). Zeroes sse + counter.
__global__ __launch_bounds__(256) void vq_prep(const float* __restrict__ cb,
                                               float* __restrict__ c2b,
                                               unsigned short* __restrict__ cbb,
                                               float* __restrict__ sse,
                                               unsigned* __restrict__ counter, int K) {
  if (blockIdx.x == 0 && threadIdx.x == 0) { *sse = 0.f; *counter = 0u; }
  int w = (int)((blockIdx.x * 256 + threadIdx.x) >> 6);
  int lane = threadIdx.x & 63;
  if (w >= K) return;
  float v = cb[(size_t)w * VQ_D + lane];
  cbb[(size_t)w * VQ_D + lane] = f2bf(v);
  float s = v * v;
#pragma unroll
  for (int off = 32; off; off >>= 1) s += __shfl_down(s, off);
  if (lane == 0) c2b[w] = s + 0.5f;
}

// Load B-frags + cc for code-tile n into (B[0..3], ccv).
#define LOADB(B, CCV, N)                                                   \
  {                                                                        \
    const int n_ = (N);                                                    \
    _Pragma("unroll") for (int s_ = 0; s_ < 4; ++s_)                       \
        B[s_] = bp8[((size_t)(n_ * 32 + c) << 3) + 2 * s_ + h];            \
    CCV = c2b[n_ * 32 + c];                                                \
  }

#define COMPUTE(B, CCV, N)                                                 \
  {                                                                        \
    f32x16 a;                                                              \
    _Pragma("unroll") for (int r_ = 0; r_ < 16; ++r_) a[r_] = CCV;         \
    _Pragma("unroll") for (int s_ = 0; s_ < 4; ++s_)                       \
        a = __builtin_amdgcn_mfma_f32_32x32x16_bf16(Af[s_], B[s_], a, 0, 0, 0); \
    const unsigned code_ = (unsigned)((N)*32 + c);                         \
    _Pragma("unroll") for (int r_ = 0; r_ < 16; ++r_)                      \
        bk[r_] = min(bk[r_], (__float_as_uint(a[r_]) & 0xFFFFFC00u) | code_); \
  }

__global__ __launch_bounds__(NTH) void vq_argmin(
    const float* __restrict__ x, const float* __restrict__ c2b,
    const unsigned short* __restrict__ cbb, int* __restrict__ gidx,
    float* __restrict__ out, float* __restrict__ sse_out,
    unsigned* __restrict__ counter, int nblocks) {
  __shared__ float redbuf[16];

  const int tid = threadIdx.x;
  const int wave = tid >> 6;
  const int lane = tid & 63;
  const int c = lane & 31;   // MFMA row/col index
  const int h = lane >> 5;   // K-half
  const long row0 = (long)blockIdx.x * MTILE + wave * 32;

  // ---- A-frags: bf16(-2x) for row (row0+c), dims [16s+8h, +8), s=0..3.
  // Lanes (c,0) and (c,1) jointly cover row c; norm summed via xor(32).
  short8 Af[4];
  float nrm = 0.f;
#pragma unroll
  for (int s = 0; s < 4; ++s) {
    const f32x4* xp = (const f32x4*)(x + (row0 + c) * VQ_D + 16 * s + 8 * h);
    f32x4 lo = xp[0];
    f32x4 hi = xp[1];
    nrm += lo[0] * lo[0] + lo[1] * lo[1] + lo[2] * lo[2] + lo[3] * lo[3];
    nrm += hi[0] * hi[0] + hi[1] * hi[1] + hi[2] * hi[2] + hi[3] * hi[3];
    short8 a;
    a[0] = (short)f2bf(-2.f * lo[0]); a[1] = (short)f2bf(-2.f * lo[1]);
    a[2] = (short)f2bf(-2.f * lo[2]); a[3] = (short)f2bf(-2.f * lo[3]);
    a[4] = (short)f2bf(-2.f * hi[0]); a[5] = (short)f2bf(-2.f * hi[1]);
    a[6] = (short)f2bf(-2.f * hi[2]); a[7] = (short)f2bf(-2.f * hi[3]);
    Af[s] = a;
  }
  nrm += __shfl_xor(nrm, 32);  // full 64-dim norm of row c in both halves

  unsigned bk[16];
#pragma unroll
  for (int r = 0; r < 16; ++r) bk[r] = 0xFFFFFFFFu;

  // ---- 32 code-tiles, double-buffered global B-frag stream (L2-resident).
  const short8* bp8 = (const short8*)cbb;
  short8 B0[4], B1[4];
  float cc0, cc1;
  LOADB(B0, cc0, 0);
#pragma unroll 2
  for (int n = 0; n < 32; n += 2) {
    LOADB(B1, cc1, n + 1);
    COMPUTE(B0, cc0, n);
    if (n + 2 < 32) LOADB(B0, cc0, n + 2);
    COMPUTE(B1, cc1, n + 1);
  }

  // ---- Reduce keys across the 32 cols (xor butterfly leaves result in all lanes).
#pragma unroll
  for (int off = 1; off < 32; off <<= 1) {
#pragma unroll
    for (int r = 0; r < 16; ++r) {
      unsigned o = (unsigned)__shfl_xor((int)bk[r], off);
      bk[r] = min(bk[r], o);
    }
  }

  // ---- Lane c extracts the key of row c: reg = (c&3)+4*(c>>3), valid when
  // ((c>>2)&1)==h  (row formula m=(reg&3)+8*(reg>>2)+4h). Static-index select.
  const int myreg = (c & 3) + 4 * (c >> 3);
  unsigned mykey = 0xFFFFFFFFu;
#pragma unroll
  for (int r = 0; r < 16; ++r)
    if (r == myreg) mykey = bk[r];

  float sse = 0.f;
  if (((c >> 2) & 1) == h) {
    gidx[row0 + c] = (int)(mykey & 1023u);
    const float s_rec = __uint_as_float(mykey & 0xFFFFFC00u);
    sse = s_rec - 0.5f + nrm;
  }
#pragma unroll
  for (int off = 32; off; off >>= 1) sse += __shfl_down(sse, off);
  if (lane == 0) redbuf[wave] = sse;
  __syncthreads();

  if (tid == 0) {
    float s = 0.f;
#pragma unroll
    for (int w = 0; w < 16; ++w) s += redbuf[w];
    atomicAdd(sse_out, s);
    __threadfence();
    unsigned old = atomicAdd(counter, 1u);
    if (old == (unsigned)(nblocks - 1)) {
      float tot = atomicAdd(sse_out, 0.f);
      long nelem = (long)nblocks * MTILE * VQ_D;
      out[nelem] = 1.25f * tot / (float)nelem;
    }
  }
}

// Pure streaming scatter: out row = exact fp32 codebook row. Hoisted idx
// loads, nontemporal stores.
__global__ __launch_bounds__(256) void vq_gather(const float* __restrict__ cb,
                                                 const int* __restrict__ gidx,
                                                 float* __restrict__ out) {
  const int t = blockIdx.x * 256 + threadIdx.x;  // 2^19 threads
  const f32x4* cb4 = (const f32x4*)cb;
  f32x4* out4 = (f32x4*)out;
  int idx[4];
#pragma unroll
  for (int i = 0; i < 4; ++i) idx[i] = gidx[(t + i * (1 << 19)) >> 4];
  f32x4 cv[4];
#pragma unroll
  for (int i = 0; i < 4; ++i) {
    const int d4 = (t + i * (1 << 19)) & 15;
    cv[i] = cb4[(size_t)idx[i] * 16 + d4];
  }
#pragma unroll
  for (int i = 0; i < 4; ++i)
    __builtin_nontemporal_store(cv[i], &out4[t + i * (1 << 19)]);
}

extern "C" void kernel_launch(void* const* d_in, const int* in_sizes, int n_in,
                              void* d_out, int out_size, void* d_ws, size_t ws_size,
                              hipStream_t stream) {
  const float* x = (const float*)d_in[0];
  const float* cb = (const float*)d_in[1];
  float* out = (float*)d_out;

  const long n_elem = (long)in_sizes[0];   // 8388608
  const int nrows = (int)(n_elem / VQ_D);  // 131072
  const int K = in_sizes[1] / VQ_D;        // 1024
  const int nblocks = nrows / MTILE;       // 256

  char* ws = (char*)d_ws;
  float* sse = (float*)ws;                             // 4 B
  unsigned* counter = (unsigned*)(ws + 64);            // 4 B
  float* c2b = (float*)(ws + 256);                     // 4 KB
  unsigned short* cbb = (unsigned short*)(ws + 8192);  // 128 KB bf16 codebook
  int* gidx = (int*)(ws + 8192 + 139264);              // 512 KB row indices

  vq_prep<<<dim3((K * 64 + 255) / 256), dim3(256), 0, stream>>>(cb, c2b, cbb, sse, counter, K);
  vq_argmin<<<dim3(nblocks), dim3(NTH), 0, stream>>>(x, c2b, cbb, gidx, out, sse, counter, nblocks);
  vq_gather<<<dim3(nrows * 16 / (256 * 4)), dim3(256), 0, stream>>>(cb, gidx, out);
}